// Round 1
// baseline (321.162 us; speedup 1.0000x reference)
//
#include <hip/hip_runtime.h>
#include <hip/hip_bf16.h>

typedef __attribute__((ext_vector_type(8))) short bf16x8;
typedef __attribute__((ext_vector_type(4))) float f32x4;
typedef unsigned short u16;

#define NP 2048
#define NREAL 2000
#define BM 128
#define BN 128
#define BK 64
#define BATCH 100000
#define EPE 200000

// ---- workspace layout (bytes) ----
#define OFF_ADJP  ((size_t)0)          // u16 [2048*2048]
#define OFF_A2P   ((size_t)8388608)    // u16 [2048*2048]  (later reused as normalized gamma bf16)
#define OFF_GRAW  ((size_t)16777216)   // f32 [2048*2048]
#define OFF_W1T   ((size_t)33554432)   // u16 [256*2048]
#define OFF_TANH  ((size_t)34603008)   // u16 [2048*256]
#define OFF_W2T   ((size_t)35651584)   // u16 [128*256]
#define OFF_D     ((size_t)35717120)   // f32 [2048]
#define OFF_PART  ((size_t)35725312)   // f32 [512]
#define OFF_H     ((size_t)35727360)   // f32 [2000*256]

__device__ __forceinline__ u16 f2b(float f) {
  union { float f; unsigned u; } v; v.f = f;
  unsigned r = v.u + 0x7fffu + ((v.u >> 16) & 1u);
  return (u16)(r >> 16);
}
__device__ __forceinline__ float b2f(u16 h) {
  union { unsigned u; float f; } v; v.u = ((unsigned)h) << 16;
  return v.f;
}

#define AS1C(p) ((const __attribute__((address_space(1))) void*)(p))
#define AS3(p)  ((__attribute__((address_space(3))) void*)(p))

// ---------------- pack kernels ----------------
__global__ __launch_bounds__(256) void pack_adj(const float* __restrict__ adj, u16* __restrict__ adjp) {
  int idx = blockIdx.x * 256 + threadIdx.x;           // 0 .. 2048*2048-1
  int r = idx >> 11, c = idx & 2047;
  float v = (r < NREAL && c < NREAL) ? adj[(size_t)r * NREAL + c] : 0.f;
  adjp[idx] = f2b(v);
}

__global__ __launch_bounds__(256) void pack_w1t(const float* __restrict__ W1, u16* __restrict__ w1t) {
  int idx = blockIdx.x * 256 + threadIdx.x;           // 256*2048
  int h = idx >> 11, k = idx & 2047;
  w1t[idx] = f2b(k < NREAL ? W1[(size_t)k * 256 + h] : 0.f);
}

__global__ __launch_bounds__(256) void pack_w2t(const float* __restrict__ W2, u16* __restrict__ w2t) {
  int idx = blockIdx.x * 256 + threadIdx.x;           // 128*256
  int d = idx >> 8, k = idx & 255;
  w2t[idx] = f2b(W2[(size_t)k * 128 + d]);
}

__global__ __launch_bounds__(256) void copy_nodeh(const float* __restrict__ ne, float* __restrict__ h) {
  int idx = blockIdx.x * 256 + threadIdx.x;           // 2000*128
  int i = idx >> 7, d = idx & 127;
  h[(size_t)i * 256 + d] = ne[idx];
}

// ---------------- bf16 MFMA GEMM (C = A * BT^T), m97-style ----------------
// A: [M][lda] bf16 row-major, BT: [Ncols][ldbt] bf16 row-major (i.e. B transposed).
// EPI 0: out bf16 + diag->dvec; 1: gamma_raw f32 (mask/divide); 2: tanh(.+b1) bf16; 3: h[:,128:] = .+b2
template <int EPI>
__global__ __launch_bounds__(256) void gemm_bt(
    const u16* __restrict__ A, const u16* __restrict__ BT,
    int K, int lda, int ldbt,
    u16* __restrict__ outb, int ldo,
    float* __restrict__ outf,
    const u16* __restrict__ adjmask,
    float* __restrict__ dvec,
    const float* __restrict__ bias,
    float* __restrict__ hout)
{
  __shared__ u16 As[BM * BK];
  __shared__ u16 Bs[BN * BK];
  const int t = threadIdx.x;
  const int w = t >> 6, lane = t & 63;
  const int brow = blockIdx.x * BM, bcol = blockIdx.y * BN;
  const int wr = w >> 1, wc = w & 1;
  const int r16 = lane & 15, kg = lane >> 4;

  f32x4 acc[4][4];
  #pragma unroll
  for (int m = 0; m < 4; m++)
    #pragma unroll
    for (int n = 0; n < 4; n++) {
      f32x4 z = {0.f, 0.f, 0.f, 0.f};
      acc[m][n] = z;
    }

  for (int k0 = 0; k0 < K; k0 += BK) {
    #pragma unroll
    for (int it = 0; it < 4; ++it) {
      int chunk = it * 256 + t;
      int row = chunk >> 3, cc = chunk & 7;
      const u16* ga = A + (size_t)(brow + row) * lda + k0 + cc * 8;
      __builtin_amdgcn_global_load_lds(AS1C(ga), AS3(As + (size_t)(it * 256 + w * 64) * 8), 16, 0, 0);
      const u16* gb = BT + (size_t)(bcol + row) * ldbt + k0 + cc * 8;
      __builtin_amdgcn_global_load_lds(AS1C(gb), AS3(Bs + (size_t)(it * 256 + w * 64) * 8), 16, 0, 0);
    }
    __syncthreads();
    #pragma unroll
    for (int kk = 0; kk < 2; ++kk) {
      bf16x8 af[4], bfr[4];
      #pragma unroll
      for (int m = 0; m < 4; m++)
        af[m] = *(const bf16x8*)&As[(wr * 64 + m * 16 + r16) * BK + kk * 32 + kg * 8];
      #pragma unroll
      for (int n = 0; n < 4; n++)
        bfr[n] = *(const bf16x8*)&Bs[(wc * 64 + n * 16 + r16) * BK + kk * 32 + kg * 8];
      #pragma unroll
      for (int m = 0; m < 4; m++)
        #pragma unroll
        for (int n = 0; n < 4; n++)
          acc[m][n] = __builtin_amdgcn_mfma_f32_16x16x32_bf16(af[m], bfr[n], acc[m][n], 0, 0, 0);
    }
    __syncthreads();
  }

  #pragma unroll
  for (int m = 0; m < 4; m++) {
    #pragma unroll
    for (int n = 0; n < 4; n++) {
      #pragma unroll
      for (int j = 0; j < 4; j++) {
        int row = brow + wr * 64 + m * 16 + kg * 4 + j;
        int col = bcol + wc * 64 + n * 16 + r16;
        float val = acc[m][n][j];
        if constexpr (EPI == 0) {
          outb[(size_t)row * ldo + col] = f2b(val);
          if (row == col) dvec[row] = val;
        } else if constexpr (EPI == 1) {
          float adjv = b2f(adjmask[(size_t)row * NP + col]);
          float p2 = dvec[row] * dvec[col];
          float g = (p2 > 0.f) ? (val * adjv) / p2 : 0.f;
          outf[(size_t)row * NP + col] = g;
        } else if constexpr (EPI == 2) {
          outb[(size_t)row * ldo + col] = f2b(tanhf(val + bias[col]));
        } else {
          if (row < NREAL) hout[(size_t)row * 256 + 128 + col] = val + bias[col];
        }
      }
    }
  }
}

// ---------------- row normalize gamma (f32 raw -> bf16) ----------------
__global__ __launch_bounds__(256) void rownorm(const float* __restrict__ graw, u16* __restrict__ gp) {
  __shared__ float red[256];
  int i = blockIdx.x;
  const float* row = graw + (size_t)i * NP;
  float vals[8];
  float s = 0.f;
  #pragma unroll
  for (int c = 0; c < 8; c++) {
    float g = row[threadIdx.x + 256 * c];
    vals[c] = g;
    s += g * g;
  }
  red[threadIdx.x] = s;
  __syncthreads();
  for (int off = 128; off > 0; off >>= 1) {
    if (threadIdx.x < off) red[threadIdx.x] += red[threadIdx.x + off];
    __syncthreads();
  }
  float norm = sqrtf(red[0]);
  float scale = 1.0f / fmaxf(norm, 1e-12f);
  u16* orow = gp + (size_t)i * NP;
  #pragma unroll
  for (int c = 0; c < 8; c++) orow[threadIdx.x + 256 * c] = f2b(vals[c] * scale);
}

// ---------------- skipgram loss ----------------
__global__ __launch_bounds__(256) void skipgram(const float* __restrict__ ne, const float* __restrict__ ce,
    const int* __restrict__ pu, const int* __restrict__ pv, const int* __restrict__ nv,
    float* __restrict__ partial) {
  __shared__ float red[256];
  int b = blockIdx.x * 256 + threadIdx.x;
  float loss = 0.f;
  if (b < BATCH) {
    const float4* u = (const float4*)(ne + (size_t)pu[b] * 128);
    const float4* v = (const float4*)(ce + (size_t)pv[b] * 128);
    const int* nvb = nv + (size_t)b * 5;
    const float4* n0 = (const float4*)(ce + (size_t)nvb[0] * 128);
    const float4* n1 = (const float4*)(ce + (size_t)nvb[1] * 128);
    const float4* n2 = (const float4*)(ce + (size_t)nvb[2] * 128);
    const float4* n3 = (const float4*)(ce + (size_t)nvb[3] * 128);
    const float4* n4 = (const float4*)(ce + (size_t)nvb[4] * 128);
    float ap = 0.f, a0 = 0.f, a1 = 0.f, a2 = 0.f, a3 = 0.f, a4 = 0.f;
    #pragma unroll 4
    for (int d = 0; d < 32; d++) {
      float4 ud = u[d];
      float4 x;
      x = v[d];  ap += ud.x * x.x + ud.y * x.y + ud.z * x.z + ud.w * x.w;
      x = n0[d]; a0 += ud.x * x.x + ud.y * x.y + ud.z * x.z + ud.w * x.w;
      x = n1[d]; a1 += ud.x * x.x + ud.y * x.y + ud.z * x.z + ud.w * x.w;
      x = n2[d]; a2 += ud.x * x.x + ud.y * x.y + ud.z * x.z + ud.w * x.w;
      x = n3[d]; a3 += ud.x * x.x + ud.y * x.y + ud.z * x.z + ud.w * x.w;
      x = n4[d]; a4 += ud.x * x.x + ud.y * x.y + ud.z * x.z + ud.w * x.w;
    }
    ap = fminf(fmaxf(ap, -10.f), 10.f);
    loss = log1pf(expf(-ap));
    a0 = fminf(fmaxf(a0, -10.f), 10.f); loss += log1pf(expf(a0));
    a1 = fminf(fmaxf(a1, -10.f), 10.f); loss += log1pf(expf(a1));
    a2 = fminf(fmaxf(a2, -10.f), 10.f); loss += log1pf(expf(a2));
    a3 = fminf(fmaxf(a3, -10.f), 10.f); loss += log1pf(expf(a3));
    a4 = fminf(fmaxf(a4, -10.f), 10.f); loss += log1pf(expf(a4));
  }
  red[threadIdx.x] = loss;
  __syncthreads();
  for (int off = 128; off > 0; off >>= 1) {
    if (threadIdx.x < off) red[threadIdx.x] += red[threadIdx.x + off];
    __syncthreads();
  }
  if (threadIdx.x == 0) partial[blockIdx.x] = red[0];
}

__global__ __launch_bounds__(256) void reduce_loss(const float* __restrict__ partial, float* __restrict__ out) {
  __shared__ float red[256];
  float s = 0.f;
  for (int i = threadIdx.x; i < 391; i += 256) s += partial[i];
  red[threadIdx.x] = s;
  __syncthreads();
  for (int off = 128; off > 0; off >>= 1) {
    if (threadIdx.x < off) red[threadIdx.x] += red[threadIdx.x + off];
    __syncthreads();
  }
  if (threadIdx.x == 0) out[0] = red[0] / (float)BATCH;
}

// ---------------- edge scores: wave per edge ----------------
__global__ __launch_bounds__(256) void edge_scores(const float* __restrict__ h,
    const int* __restrict__ ps, const int* __restrict__ pd,
    const int* __restrict__ ns, const int* __restrict__ nd,
    float* __restrict__ out) {
  int w = threadIdx.x >> 6, lane = threadIdx.x & 63;
  int e = blockIdx.x * 4 + w;
  if (e >= 2 * EPE) return;
  int src, dst;
  if (e < EPE) { src = ps[e]; dst = pd[e]; }
  else         { src = ns[e - EPE]; dst = nd[e - EPE]; }
  const float4* hs = (const float4*)(h + (size_t)src * 256);
  const float4* hd = (const float4*)(h + (size_t)(1000 + dst) * 256);
  float4 a = hs[lane], b = hd[lane];
  float p = a.x * b.x + a.y * b.y + a.z * b.z + a.w * b.w;
  #pragma unroll
  for (int off = 32; off > 0; off >>= 1) p += __shfl_xor(p, off, 64);
  if (lane == 0) out[1 + e] = p;
}

// ---------------- launch ----------------
extern "C" void kernel_launch(void* const* d_in, const int* in_sizes, int n_in,
                              void* d_out, int out_size, void* d_ws, size_t ws_size,
                              hipStream_t stream) {
  const float* node_embed    = (const float*)d_in[0];
  const float* context_embed = (const float*)d_in[1];
  const float* adj           = (const float*)d_in[2];
  const float* W1            = (const float*)d_in[3];
  const float* b1            = (const float*)d_in[4];
  const float* W2            = (const float*)d_in[5];
  const float* b2            = (const float*)d_in[6];
  const int* pos_u   = (const int*)d_in[7];
  const int* pos_v   = (const int*)d_in[8];
  const int* neg_v   = (const int*)d_in[9];
  const int* pos_src = (const int*)d_in[10];
  const int* pos_dst = (const int*)d_in[11];
  const int* neg_src = (const int*)d_in[12];
  const int* neg_dst = (const int*)d_in[13];
  float* out = (float*)d_out;

  char* ws = (char*)d_ws;
  u16*   adjp  = (u16*)(ws + OFF_ADJP);
  u16*   a2p   = (u16*)(ws + OFF_A2P);
  float* graw  = (float*)(ws + OFF_GRAW);
  u16*   w1t   = (u16*)(ws + OFF_W1T);
  u16*   tanhb = (u16*)(ws + OFF_TANH);
  u16*   w2t   = (u16*)(ws + OFF_W2T);
  float* dvec  = (float*)(ws + OFF_D);
  float* part  = (float*)(ws + OFF_PART);
  float* h     = (float*)(ws + OFF_H);

  // pack / transpose / copy
  pack_adj<<<16384, 256, 0, stream>>>(adj, adjp);
  pack_w1t<<<2048, 256, 0, stream>>>(W1, w1t);
  pack_w2t<<<128, 256, 0, stream>>>(W2, w2t);
  copy_nodeh<<<1000, 256, 0, stream>>>(node_embed, h);

  // A2 = adj @ adj (exact in bf16 MFMA; adj symmetric so BT = adj)
  gemm_bt<0><<<dim3(16, 16), 256, 0, stream>>>(adjp, adjp, NP, NP, NP,
                                               a2p, NP, nullptr, nullptr, dvec, nullptr, nullptr);
  // gamma_raw = (A2 @ adj) * adj / (d_i d_j)
  gemm_bt<1><<<dim3(16, 16), 256, 0, stream>>>(a2p, adjp, NP, NP, NP,
                                               nullptr, 0, graw, adjp, dvec, nullptr, nullptr);
  // row-normalize -> bf16 gamma (reuse a2p buffer)
  rownorm<<<NREAL, 256, 0, stream>>>(graw, a2p);
  // tanh(gamma @ W1 + b1)
  gemm_bt<2><<<dim3(16, 2), 256, 0, stream>>>(a2p, w1t, NP, NP, NP,
                                              tanhb, 256, nullptr, nullptr, nullptr, b1, nullptr);
  // h[:,128:] = tanh @ W2 + b2
  gemm_bt<3><<<dim3(16, 1), 256, 0, stream>>>(tanhb, w2t, 256, 256, 256,
                                              nullptr, 0, nullptr, nullptr, nullptr, b2, h);

  // skipgram loss (deterministic two-stage reduction)
  skipgram<<<391, 256, 0, stream>>>(node_embed, context_embed, pos_u, pos_v, neg_v, part);
  reduce_loss<<<1, 256, 0, stream>>>(part, out);

  // edge scores
  edge_scores<<<100000, 256, 0, stream>>>(h, pos_src, pos_dst, neg_src, neg_dst, out);
}